// Round 2
// baseline (415.593 us; speedup 1.0000x reference)
//
#include <hip/hip_runtime.h>
#include <hip/hip_bf16.h>

#define NTOK 16384
#define HD   4096
#define NE   64
#define TTILE 32            // tokens per block
#define NBLK (NTOK / TTILE) // 512 blocks -> 2 blocks/CU

typedef __bf16 bf16x8 __attribute__((ext_vector_type(8)));
typedef __bf16 bf16x4 __attribute__((ext_vector_type(4)));
typedef float  f32x4  __attribute__((ext_vector_type(4)));

__device__ __forceinline__ f32x4 mfma16(bf16x8 a, bf16x8 b, f32x4 c) {
    return __builtin_amdgcn_mfma_f32_16x16x32_bf16(a, b, c, 0, 0, 0);
}

// LDS row strides (elements)
#define SAB 40   // bf16: 32 K-elems + 8 pad -> 80 B rows, 16B-aligned
#define SL  68   // float stride for logits tile (32 x 64)

__device__ __forceinline__ void cvt_split(float4 v, bf16x4& hi, bf16x4& lo) {
    float x[4] = {v.x, v.y, v.z, v.w};
    #pragma unroll
    for (int e = 0; e < 4; ++e) {
        __bf16 h = (__bf16)x[e];        // RNE
        hi[e] = h;
        lo[e] = (__bf16)(x[e] - (float)h);
    }
}

__global__ void zero_ws_kernel(float* ws) {
    int i = threadIdx.x;
    if (i < 129) ws[i] = 0.0f;   // [0,64)=P_sum, [64,128)=counts, [128]=z_sum
}

__global__ __launch_bounds__(256) void router_kernel(
    const float* __restrict__ hs,
    const float* __restrict__ Wg,
    float* __restrict__ out,
    float* __restrict__ ws)
{
    // A tiles: 2buf x hi/lo x 32 rows -> 10,240 B ; B tiles: 64 rows -> 20,480 B
    __shared__ __bf16 sAhi[2][TTILE * SAB];
    __shared__ __bf16 sAlo[2][TTILE * SAB];
    __shared__ __bf16 sBhi[2][NE * SAB];
    __shared__ __bf16 sBlo[2][NE * SAB];
    __shared__ float  sLog[TTILE * SL];   // 8,704 B
    __shared__ float  sInv[TTILE];
    __shared__ float  sPp[4 * 64];
    __shared__ float  sCnt[64];
    __shared__ float  sZ;
    // total ~50 KB -> 2 blocks/CU co-resident at grid 512

    const int tid = threadIdx.x;
    const int t0  = blockIdx.x * TTILE;

    if (tid < 64) sCnt[tid] = 0.0f;
    if (tid == 0) sZ = 0.0f;

    // ---- staging: per iter each thread loads 1 float4 of A + 2 float4 of B
    const int r1 = tid >> 3;            // 0..31
    const int c4 = (tid & 7) * 4;       // k offset (floats)
    const float* gA = hs + (size_t)(t0 + r1) * HD + c4;
    const float* gB = Wg + (size_t)r1 * HD + c4;
    const int oA  = r1 * SAB + c4;
    const int oB1 = r1 * SAB + c4;
    const int oB2 = (r1 + 32) * SAB + c4;

    // ---- wave tile: 16 tok x 32 exp (1x2 MFMA tiles), 4 waves cover 32x64
    const int lane = tid & 63;
    const int wv   = tid >> 6;
    const int wr   = (wv >> 1) * 16;    // token offset: 0 or 16
    const int wc   = (wv & 1) * 32;     // expert offset: 0 or 32
    const int fm   = lane & 15;
    const int fq   = lane >> 4;         // 0..3
    const int fk   = fq * 8;

    f32x4 acc[2];
    acc[0] = (f32x4){0.f, 0.f, 0.f, 0.f};
    acc[1] = (f32x4){0.f, 0.f, 0.f, 0.f};

    // ---- prologue: stage k-tile 0 into buffer 0
    {
        float4 a0 = *(const float4*)(gA);
        float4 b0 = *(const float4*)(gB);
        float4 b1 = *(const float4*)(gB + 32 * HD);
        bf16x4 h, l;
        cvt_split(a0, h, l); *(bf16x4*)&sAhi[0][oA]  = h; *(bf16x4*)&sAlo[0][oA]  = l;
        cvt_split(b0, h, l); *(bf16x4*)&sBhi[0][oB1] = h; *(bf16x4*)&sBlo[0][oB1] = l;
        cvt_split(b1, h, l); *(bf16x4*)&sBhi[0][oB2] = h; *(bf16x4*)&sBlo[0][oB2] = l;
    }
    __syncthreads();

    const int NIT = HD / 32;   // 128
    for (int it = 0; it < NIT; ++it) {
        const int cur = it & 1;
        const bool more = (it + 1) < NIT;
        float4 na0, nb0, nb1;
        if (more) {
            const int k0 = (it + 1) * 32;
            na0 = *(const float4*)(gA + k0);
            nb0 = *(const float4*)(gB + k0);
            nb1 = *(const float4*)(gB + 32 * HD + k0);
        }

        // ---- compute on current buffer: 6 ds_read_b128, 8 MFMAs (4-term exact split)
        bf16x8 ahi, alo, bhi[2], blo[2];
        {
            const int aoff = (wr + fm) * SAB + fk;
            ahi = *(const bf16x8*)&sAhi[cur][aoff];
            alo = *(const bf16x8*)&sAlo[cur][aoff];
        }
        #pragma unroll
        for (int j = 0; j < 2; ++j) {
            const int boff = (wc + j * 16 + fm) * SAB + fk;
            bhi[j] = *(const bf16x8*)&sBhi[cur][boff];
            blo[j] = *(const bf16x8*)&sBlo[cur][boff];
        }
        #pragma unroll
        for (int j = 0; j < 2; ++j) {
            acc[j] = mfma16(ahi, bhi[j], acc[j]);
            acc[j] = mfma16(ahi, blo[j], acc[j]);
            acc[j] = mfma16(alo, bhi[j], acc[j]);
            acc[j] = mfma16(alo, blo[j], acc[j]);   // 4th term: error -> fp32 noise
        }

        if (more) {
            const int nb = cur ^ 1;
            bf16x4 h, l;
            cvt_split(na0, h, l); *(bf16x4*)&sAhi[nb][oA]  = h; *(bf16x4*)&sAlo[nb][oA]  = l;
            cvt_split(nb0, h, l); *(bf16x4*)&sBhi[nb][oB1] = h; *(bf16x4*)&sBlo[nb][oB1] = l;
            cvt_split(nb1, h, l); *(bf16x4*)&sBhi[nb][oB2] = h; *(bf16x4*)&sBlo[nb][oB2] = l;
        }
        __syncthreads();
    }

    // ---- scatter logits to LDS: C/D layout col=lane&15 (expert), row=fq*4+reg (token)
    #pragma unroll
    for (int j = 0; j < 2; ++j)
        #pragma unroll
        for (int r = 0; r < 4; ++r) {
            const int tokl = wr + fq * 4 + r;
            const int expl = wc + j * 16 + fm;
            sLog[tokl * SL + expl] = acc[j][r];
        }
    __syncthreads();

    // ---- phase 2a: softmax/top-2; 8 lanes per token, 8 experts per lane
    const int g = tid >> 3;       // token 0..31
    const int l = tid & 7;
    float* Lrow = &sLog[g * SL + l * 8];
    float lv[8];
    float m = -3.0e38f;
    #pragma unroll
    for (int c = 0; c < 8; ++c) { lv[c] = Lrow[c]; m = fmaxf(m, lv[c]); }
    m = fmaxf(m, __shfl_xor(m, 1, 64));
    m = fmaxf(m, __shfl_xor(m, 2, 64));
    m = fmaxf(m, __shfl_xor(m, 4, 64));

    float v1 = -3.0e38f, v2 = -3.0e38f; int i1 = 0, i2 = 0;
    float ssum = 0.0f;
    #pragma unroll
    for (int c = 0; c < 8; ++c) {
        const float val = lv[c]; const int idx = l * 8 + c;
        const float ev = __expf(val - m);
        Lrow[c] = ev;               // overwrite logits with exp(l - m)
        ssum += ev;
        if (val > v1) { v2 = v1; i2 = i1; v1 = val; i1 = idx; }
        else if (val > v2) { v2 = val; i2 = idx; }
    }
    ssum += __shfl_xor(ssum, 1, 64);
    ssum += __shfl_xor(ssum, 2, 64);
    ssum += __shfl_xor(ssum, 4, 64);

    #pragma unroll
    for (int s = 1; s <= 4; s <<= 1) {
        const float ov1 = __shfl_xor(v1, s, 64);
        const int   oi1 = __shfl_xor(i1, s, 64);
        const float ov2 = __shfl_xor(v2, s, 64);
        const int   oi2 = __shfl_xor(i2, s, 64);
        float n1, n2; int ni1, ni2;
        const bool ofirst = (ov1 > v1) || (ov1 == v1 && oi1 < i1);
        if (ofirst) {
            n1 = ov1; ni1 = oi1;
            const bool osec = (ov2 > v1) || (ov2 == v1 && oi2 < i1);
            n2 = osec ? ov2 : v1; ni2 = osec ? oi2 : i1;
        } else {
            n1 = v1; ni1 = i1;
            const bool asec = (v2 > ov1) || (v2 == ov1 && i2 < oi1);
            n2 = asec ? v2 : ov1; ni2 = asec ? i2 : oi1;
        }
        v1 = n1; i1 = ni1; v2 = n2; i2 = ni2;
    }

    if (l == 0) {
        const float e1 = __expf(v1 - m), e2 = __expf(v2 - m);
        const float winv = 1.0f / (e1 + e2);
        const int token = t0 + g;
        out[2 * token]     = e1 * winv;
        out[2 * token + 1] = e2 * winv;
        out[2 * NTOK + 2 * token]     = (float)i1;   // indices as f32 (concat promotion)
        out[2 * NTOK + 2 * token + 1] = (float)i2;
        const float lse = m + __logf(ssum);
        atomicAdd(&sZ, lse * lse);
        atomicAdd(&sCnt[i1], 1.0f);
        atomicAdd(&sCnt[i2], 1.0f);
        sInv[g] = 1.0f / ssum;
    }
    __syncthreads();

    // ---- phase 2b: block-local P sums over 32 tokens, then global atomics
    {
        const int e = tid & 63;
        const int q = tid >> 6;
        float part = 0.0f;
        #pragma unroll
        for (int t = 0; t < 8; ++t) {
            const int tok = q * 8 + t;
            part += sLog[tok * SL + e] * sInv[tok];
        }
        sPp[q * 64 + e] = part;
    }
    __syncthreads();
    if (tid < 64) {
        const float ps = sPp[tid] + sPp[64 + tid] + sPp[128 + tid] + sPp[192 + tid];
        atomicAdd(&ws[tid], ps);             // sum of probs per expert
        atomicAdd(&ws[64 + tid], sCnt[tid]); // top-2 counts per expert
    }
    if (tid == 0) atomicAdd(&ws[128], sZ);
}

__global__ void finalize_kernel(const float* __restrict__ ws, float* __restrict__ out) {
    const int e = threadIdx.x;   // 64 threads, one wave
    const float P = ws[e] * (1.0f / NTOK);
    const float f = ws[64 + e] * (1.0f / (NTOK * 2));
    float term = f * P;
    #pragma unroll
    for (int s = 32; s >= 1; s >>= 1) term += __shfl_xor(term, s, 64);
    if (e == 0) {
        const float lb = 64.0f * term;
        const float z  = ws[128] * (1.0f / NTOK);
        out[4 * NTOK] = 0.001f * lb + 0.001f * z;
    }
}

extern "C" void kernel_launch(void* const* d_in, const int* in_sizes, int n_in,
                              void* d_out, int out_size, void* d_ws, size_t ws_size,
                              hipStream_t stream) {
    const float* hs = (const float*)d_in[0];
    const float* Wg = (const float*)d_in[1];
    float* out = (float*)d_out;
    float* ws  = (float*)d_ws;

    hipLaunchKernelGGL(zero_ws_kernel, dim3(1), dim3(256), 0, stream, ws);
    hipLaunchKernelGGL(router_kernel, dim3(NBLK), dim3(256), 0, stream, hs, Wg, out, ws);
    hipLaunchKernelGGL(finalize_kernel, dim3(1), dim3(64), 0, stream, ws, out);
}